// Round 20
// baseline (394.558 us; speedup 1.0000x reference)
//
#include <hip/hip_runtime.h>
#include <hip/hip_bf16.h>
#include <stdint.h>

// ProjectiveAttention: out = softmax(h @ W @ h^T) @ h
// B=8, S=2048, D=800, all fp32 in/out.
// R10: conflict-free 32-wide swizzle. R12-R15: fused split3, single barrier,
// K=800 exact. R16/R19: gemmS BM=256 wave 128x64 streaming (80.8us, VERBATIM
// - R17/R18 proved touching its template body causes spill regression).
// R20: PV-8 as a STANDALONE kernel gemmP (non-split BM=256xBN=256, wave
// 128x64, 12 reads/32 MFMA, 64KB dbuf, single 16384-row dispatch) fed by a
// compact bf16 attn buffer (softmax gains out ptr/pitch). ws-adaptive
// fallback to the R19 gemmT path. gemmS/gemmT byte-identical to R19.

#define BB 8
#define SS 2048
#define DD 800            // K = pitch = 800 u16 (1600B, 16B-aligned rows)
#define M1 (BB*SS)        // 16384

typedef unsigned short u16;
typedef __attribute__((ext_vector_type(8))) short bf16x8;
typedef __attribute__((ext_vector_type(4))) float f32x4;

#define MFMA16(A, B, C) __builtin_amdgcn_mfma_f32_16x16x32_bf16(A, B, C, 0, 0, 0)
#define VMF(N) asm volatile("s_waitcnt vmcnt(" #N ")" ::: "memory")
#define BAR() __builtin_amdgcn_s_barrier()

template <int SPW>
__device__ __forceinline__ void vmf_spw() {
    static_assert(SPW == 3 || SPW == 4 || SPW == 6, "unsupported SPW");
    if constexpr (SPW == 6) { VMF(6); }
    else if constexpr (SPW == 4) { VMF(4); }
    else { VMF(3); }
}

__device__ __forceinline__ u16 f2bf(float x) {
    uint32_t u = __float_as_uint(x);
    uint32_t r = (u + 0x7fffu + ((u >> 16) & 1u)) >> 16;  // RTN-even
    return (u16)r;
}
__device__ __forceinline__ float bf2f(u16 h) {
    return __uint_as_float(((uint32_t)h) << 16);
}
__device__ __forceinline__ void gload16(const void* g, void* l) {
    __builtin_amdgcn_global_load_lds((__attribute__((address_space(1))) void*)g,
                                     (__attribute__((address_space(3))) void*)l,
                                     16, 0, 0);
}

// ---------------- prep kernels (R19 verbatim) ----------------

__global__ __launch_bounds__(256) void hsplit_kernel(const float* __restrict__ x,
                                                     u16* __restrict__ hi,
                                                     u16* __restrict__ lo) {
    long i = (long)blockIdx.x * 256 + threadIdx.x;   // 16384*200 float4 groups
    float4 v = *(const float4*)(x + i * 4);
    u16 h0 = f2bf(v.x), h1 = f2bf(v.y), h2 = f2bf(v.z), h3 = f2bf(v.w);
    ushort4 hv = {h0, h1, h2, h3};
    ushort4 lv = {f2bf(v.x - bf2f(h0)), f2bf(v.y - bf2f(h1)),
                  f2bf(v.z - bf2f(h2)), f2bf(v.w - bf2f(h3))};
    *(ushort4*)(hi + i * 4) = hv;
    *(ushort4*)(lo + i * 4) = lv;
}

__global__ __launch_bounds__(256) void wsplit_kernel(const float* __restrict__ W,
                                                     u16* __restrict__ hi,
                                                     u16* __restrict__ lo) {
    int idx = blockIdx.x * 256 + threadIdx.x;   // 1024*800
    int e = idx / DD, d = idx - e * DD;
    float v = (e < DD) ? W[(long)d * DD + e] : 0.f;
    u16 h = f2bf(v);
    hi[idx] = h;
    lo[idx] = f2bf(v - bf2f(h));
}

__global__ void transpose_kernel(const u16* __restrict__ h_hi, u16* __restrict__ hT) {
    __shared__ u16 tile[32][33];
    int b = blockIdx.z;
    int t0 = blockIdx.x * 32, d0 = blockIdx.y * 32;
    int lx = threadIdx.x, ly = threadIdx.y;
    for (int i = ly; i < 32; i += 8) {
        int d = d0 + lx;
        tile[i][lx] = (d < DD) ? h_hi[((long)b * SS + t0 + i) * DD + d] : (u16)0;
    }
    __syncthreads();
    for (int i = ly; i < 32; i += 8) {
        hT[((long)b * 1024 + d0 + i) * SS + t0 + lx] = tile[lx][i];
    }
}

// ---------------- softmax: fp32 scores row -> bf16 attn row (out ptr/pitch) ----

__global__ __launch_bounds__(256) void softmax_kernel(const float* __restrict__ scores,
                                                      u16* __restrict__ attn,
                                                      long opitch) {
    const long row = blockIdx.x;
    const float* p = scores + row * (long)SS;
    const int tid = threadIdx.x;
    const int lane = tid & 63, wid = tid >> 6;
    __shared__ float red[8];

    float4 v0 = *(const float4*)(p + 8 * tid);
    float4 v1 = *(const float4*)(p + 8 * tid + 4);
    float v[8] = {v0.x, v0.y, v0.z, v0.w, v1.x, v1.y, v1.z, v1.w};
    float mx = -3.4e38f;
#pragma unroll
    for (int j = 0; j < 8; ++j) mx = fmaxf(mx, v[j]);
#pragma unroll
    for (int o = 32; o; o >>= 1) mx = fmaxf(mx, __shfl_xor(mx, o, 64));
    if (lane == 0) red[wid] = mx;
    __syncthreads();
    mx = fmaxf(fmaxf(red[0], red[1]), fmaxf(red[2], red[3]));

    float sum = 0.f;
#pragma unroll
    for (int j = 0; j < 8; ++j) { v[j] = __expf(v[j] - mx); sum += v[j]; }
#pragma unroll
    for (int o = 32; o; o >>= 1) sum += __shfl_xor(sum, o, 64);
    if (lane == 0) red[4 + wid] = sum;
    __syncthreads();
    const float inv = 1.f / (red[4] + red[5] + red[6] + red[7]);

    u16* ap = attn + row * opitch;   // reads done before barriers -> in-place safe
    ushort4 w0 = {f2bf(v[0] * inv), f2bf(v[1] * inv), f2bf(v[2] * inv), f2bf(v[3] * inv)};
    ushort4 w1 = {f2bf(v[4] * inv), f2bf(v[5] * inv), f2bf(v[6] * inv), f2bf(v[7] * inv)};
    *(ushort4*)(ap + 8 * tid) = w0;
    *(ushort4*)(ap + 8 * tid + 4) = w1;
}

// ---------------- gemmS: split3-fused, BM=256 x BN=256, BK=32, 8 waves ---------
// R19 VERBATIM (do not touch - R17/R18 spill lesson).

template <int SPLIT_OUT, int NGUARD>
__global__ __launch_bounds__(512, 2) void gemmS(
    const u16* __restrict__ Ahi, const u16* __restrict__ Alo, int lda,
    const u16* __restrict__ Bhi, const u16* __restrict__ Blo, long sB, int ldb,
    float* __restrict__ C, u16* __restrict__ Chi, u16* __restrict__ Clo,
    int ldc, int Nlim, int ksteps, int gmt) {
    extern __shared__ u16 smem[];          // [2][32768]

    const int tid = threadIdx.x;
    const int lane = tid & 63, wid = tid >> 6;
    const int wm = wid >> 2, wn = wid & 3;

    // bijective XCD remap (m204)
    const int nwg = gridDim.x;
    const int orig = blockIdx.x;
    const int q = nwg >> 3, r = nwg & 7;
    const int xcd = orig & 7;
    const int wg = (xcd < r ? xcd * (q + 1) : r * (q + 1) + (xcd - r) * q) + (orig >> 3);
    const int m0 = (wg % gmt) * 256;
    const int n0 = (wg / gmt) * 256;

    const long boff = sB ? (long)(m0 >> 11) * sB : 0;
    const u16* Bh = Bhi + boff;
    const u16* Bl = Blo + boff;

    const int sr = lane >> 2;
    const int sc = ((lane & 3) * 8) ^ (((lane >> 3) & 3) << 3);
    const int rdo = (lane & 15) * 32 + (((lane >> 4) * 8) ^ (((lane >> 1) & 3) << 3));

    // per-wave staging source (wave's 8 cells are all in one part)
    const int part = wid >> 1;             // 0 Ahi, 1 Alo, 2 Bhi, 3 Blo
    const u16* psrc = (part == 0) ? Ahi : (part == 1) ? Alo : (part == 2) ? Bh : Bl;
    const int pbase = (part < 2) ? m0 : n0;
    const int pld = (part < 2) ? lda : ldb;
    const int crow0 = (wid & 1) * 8;       // first local cell (of 16 in part)

    f32x4 acc[8][4];
#pragma unroll
    for (int i = 0; i < 8; ++i)
#pragma unroll
        for (int j = 0; j < 4; ++j) acc[i][j] = (f32x4){0.f, 0.f, 0.f, 0.f};

    auto stage = [&](int t, u16* bp) {
        const int kb = t * 32;
#pragma unroll
        for (int k = 0; k < 8; ++k) {
            const int c = crow0 + k;
            gload16(psrc + (long)(pbase + c * 16 + sr) * pld + kb + sc,
                    bp + (part * 16 + c) * 512 + lane * 8);
        }
    };

    stage(0, smem);
    VMF(0);
    BAR();

    for (int t = 0; t < ksteps; ++t) {
        u16* bp = smem + (t & 1) * 32768;
        const bool h1 = (t + 1 < ksteps);
        if (h1) stage(t + 1, smem + ((t + 1) & 1) * 32768);

        bf16x8 a[8], bh4[4], bl4[4];
#pragma unroll
        for (int j = 0; j < 4; ++j) {
            bh4[j] = *(const bf16x8*)(bp + (32 + wn * 4 + j) * 512 + rdo);
            bl4[j] = *(const bf16x8*)(bp + (48 + wn * 4 + j) * 512 + rdo);
        }
#pragma unroll
        for (int i = 0; i < 8; ++i)
            a[i] = *(const bf16x8*)(bp + (wm * 8 + i) * 512 + rdo);

        __builtin_amdgcn_s_setprio(1);
#pragma unroll
        for (int i = 0; i < 8; ++i)   // v0: hh
#pragma unroll
            for (int j = 0; j < 4; ++j) acc[i][j] = MFMA16(a[i], bh4[j], acc[i][j]);
#pragma unroll
        for (int i = 0; i < 8; ++i)   // v1: hl
#pragma unroll
            for (int j = 0; j < 4; ++j) acc[i][j] = MFMA16(a[i], bl4[j], acc[i][j]);
        __builtin_amdgcn_s_setprio(0);

#pragma unroll
        for (int i = 0; i < 8; ++i)   // reload: Alo (reuses a regs)
            a[i] = *(const bf16x8*)(bp + (16 + wm * 8 + i) * 512 + rdo);

        __builtin_amdgcn_s_setprio(1);
#pragma unroll
        for (int i = 0; i < 8; ++i)   // v2: lh
#pragma unroll
            for (int j = 0; j < 4; ++j) acc[i][j] = MFMA16(a[i], bh4[j], acc[i][j]);
        __builtin_amdgcn_s_setprio(0);

        if (h1) { VMF(0); }           // drains stage(t+1), issued ~full iter ago
        BAR();
    }

    // epilogue: C/D layout col=lane&15, row=(lane>>4)*4+reg (R1-verified)
    const int rlane = lane & 15;
    const int crow = m0 + wm * 128 + (lane >> 4) * 4;
    const int ccol = n0 + wn * 64 + rlane;
#pragma unroll
    for (int i = 0; i < 8; ++i) {
#pragma unroll
        for (int j = 0; j < 4; ++j) {
            const int nn = ccol + j * 16;
            if (NGUARD && nn >= Nlim) continue;
#pragma unroll
            for (int rr = 0; rr < 4; ++rr) {
                const int mm = crow + i * 16 + rr;
                const long off = (long)mm * ldc + nn;
                float v = acc[i][j][rr];
                if (SPLIT_OUT) {
                    u16 hh = f2bf(v);
                    Chi[off] = hh;
                    Clo[off] = f2bf(v - bf2f(hh));
                } else {
                    C[off] = v;
                }
            }
        }
    }
}

// ---------------- gemmT (PV fallback): R19 verbatim ---------------------------

template <int BN, int WN, int SPLIT_OUT, int NGUARD>
__global__ __launch_bounds__(128 * WN, 4) void gemmT(
    const u16* __restrict__ Ahi, int lda,
    const u16* __restrict__ Bhi, long sB, int ldb,
    float* __restrict__ C,
    int ldc, int Nlim, int Nbuf, int ksteps, int gmt) {
    constexpr int NCA = 8;
    constexpr int NCB = BN / 16;
    constexpr int BUFU = (NCA + NCB) * 512;
    constexpr int W = 2 * WN;
    constexpr int SPW = (NCA + NCB) / W;
    extern __shared__ u16 smem[];          // [3][BUFU]

    const int tid = threadIdx.x;
    const int lane = tid & 63, wid = tid >> 6;
    const int wm = wid / WN, wn = wid % WN;

    const int nwg = gridDim.x;
    const int orig = blockIdx.x;
    const int q = nwg >> 3, r = nwg & 7;
    const int xcd = orig & 7;
    const int wg = (xcd < r ? xcd * (q + 1) : r * (q + 1) + (xcd - r) * q) + (orig >> 3);
    const int m0 = (wg % gmt) * 128;
    const int n0 = (wg / gmt) * BN;

    const long boff = sB ? (long)(m0 >> 11) * sB : 0;
    const u16* Bh = Bhi + boff;

    const int sr = lane >> 2;
    const int sc = ((lane & 3) * 8) ^ (((lane >> 3) & 3) << 3);
    const int rdo = (lane & 15) * 32 + (((lane >> 4) * 8) ^ (((lane >> 1) & 3) << 3));

    f32x4 acc[4][4];
#pragma unroll
    for (int i = 0; i < 4; ++i)
#pragma unroll
        for (int j = 0; j < 4; ++j) acc[i][j] = (f32x4){0.f, 0.f, 0.f, 0.f};

    auto stage = [&](int t, u16* bp) {
        const int kb = t * 32;
        constexpr int APW = NCA / W, BPW = NCB / W;
#pragma unroll
        for (int i = 0; i < APW; ++i) {
            const int c = wid * APW + i;
            gload16(Ahi + (long)(m0 + c * 16 + sr) * lda + kb + sc,
                    bp + c * 512 + lane * 8);
        }
#pragma unroll
        for (int j = 0; j < BPW; ++j) {
            const int c = wid * BPW + j;
            gload16(Bh + (long)(n0 + c * 16 + sr) * ldb + kb + sc,
                    bp + (NCA + c) * 512 + lane * 8);
        }
    };

    stage(0, smem);
    if (ksteps > 1) stage(1, smem + BUFU);
    vmf_spw<SPW>();
    BAR();

    int bufi = 0;
    for (int t = 0; t < ksteps; ++t) {
        u16* bp = smem + bufi * BUFU;
        const bool h2 = (t + 2 < ksteps);
        if (h2) {
            int nb = bufi + 2; if (nb >= 3) nb -= 3;
            stage(t + 2, smem + nb * BUFU);
        }
        bf16x8 a[4], b[4];
#pragma unroll
        for (int i = 0; i < 4; ++i)
            a[i] = *(const bf16x8*)(bp + (wm * 4 + i) * 512 + rdo);
#pragma unroll
        for (int j = 0; j < 4; ++j)
            b[j] = *(const bf16x8*)(bp + (NCA + wn * 4 + j) * 512 + rdo);
        __builtin_amdgcn_s_setprio(1);
#pragma unroll
        for (int i = 0; i < 4; ++i)
#pragma unroll
            for (int j = 0; j < 4; ++j) acc[i][j] = MFMA16(a[i], b[j], acc[i][j]);
        __builtin_amdgcn_s_setprio(0);
        if (h2) {
            vmf_spw<SPW>();
        } else if (t + 1 < ksteps) {
            VMF(0);
        }
        BAR();
        ++bufi; if (bufi == 3) bufi = 0;
    }

    const int rlane = lane & 15;
    const int crow = m0 + wm * 64 + (lane >> 4) * 4;
    const int ccol = n0 + wn * 64 + rlane;
#pragma unroll
    for (int i = 0; i < 4; ++i) {
#pragma unroll
        for (int j = 0; j < 4; ++j) {
            const int nn = ccol + j * 16;
            if (NGUARD && nn >= Nbuf) continue;
#pragma unroll
            for (int rr = 0; rr < 4; ++rr) {
                const int mm = crow + i * 16 + rr;
                float v = acc[i][j][rr];
                if (NGUARD && nn >= Nlim) v = 0.f;
                C[(long)mm * ldc + nn] = v;
            }
        }
    }
}

// ---------------- gemmP (PV-8): standalone non-split big-tile ------------------
// BM=256 x BN=256, BK=32, 8 waves, wave 128x64, 12 reads -> 32 MFMA/iter.
// LDS: [2 dbuf][32 cells][512 u16] = 64KB. Cells: A 0-15, B 16-31.
// Same cell swizzle / staging involution as gemmS (R10-verified).
// M spans all 8 batches (batch = m0>>11 selects hT batch panel).

__global__ __launch_bounds__(512, 2) void gemmP(
    const u16* __restrict__ A, int lda,
    const u16* __restrict__ Bmat, long sB, int ldb,
    float* __restrict__ C, int ldc, int Nlim, int ksteps, int gmt) {
    extern __shared__ u16 smem[];          // [2][16384]

    const int tid = threadIdx.x;
    const int lane = tid & 63, wid = tid >> 6;
    const int wm = wid >> 2, wn = wid & 3;

    // bijective XCD remap (m204)
    const int nwg = gridDim.x;
    const int orig = blockIdx.x;
    const int q = nwg >> 3, r = nwg & 7;
    const int xcd = orig & 7;
    const int wg = (xcd < r ? xcd * (q + 1) : r * (q + 1) + (xcd - r) * q) + (orig >> 3);
    const int m0 = (wg % gmt) * 256;
    const int n0 = (wg / gmt) * 256;

    const u16* Bh = Bmat + (long)(m0 >> 11) * sB;

    const int sr = lane >> 2;
    const int sc = ((lane & 3) * 8) ^ (((lane >> 3) & 3) << 3);
    const int rdo = (lane & 15) * 32 + (((lane >> 4) * 8) ^ (((lane >> 1) & 3) << 3));

    // staging: part = wid>>2 (0 A, 1 B), 4 cells per wave
    const int part = wid >> 2;
    const u16* psrc = (part == 0) ? A : Bh;
    const int pbase = (part == 0) ? m0 : n0;
    const int pld = (part == 0) ? lda : ldb;
    const int c0 = (wid & 3) * 4;

    f32x4 acc[8][4];
#pragma unroll
    for (int i = 0; i < 8; ++i)
#pragma unroll
        for (int j = 0; j < 4; ++j) acc[i][j] = (f32x4){0.f, 0.f, 0.f, 0.f};

    auto stage = [&](int t, u16* bp) {
        const int kb = t * 32;
#pragma unroll
        for (int k = 0; k < 4; ++k) {
            const int c = c0 + k;
            gload16(psrc + (long)(pbase + c * 16 + sr) * pld + kb + sc,
                    bp + (part * 16 + c) * 512 + lane * 8);
        }
    };

    stage(0, smem);
    VMF(0);
    BAR();

    for (int t = 0; t < ksteps; ++t) {
        u16* bp = smem + (t & 1) * 16384;
        const bool h1 = (t + 1 < ksteps);
        if (h1) stage(t + 1, smem + ((t + 1) & 1) * 16384);

        bf16x8 a[8], b4[4];
#pragma unroll
        for (int j = 0; j < 4; ++j)
            b4[j] = *(const bf16x8*)(bp + (16 + wn * 4 + j) * 512 + rdo);
#pragma unroll
        for (int i = 0; i < 8; ++i)
            a[i] = *(const bf16x8*)(bp + (wm * 8 + i) * 512 + rdo);

        __builtin_amdgcn_s_setprio(1);
#pragma unroll
        for (int i = 0; i < 8; ++i)
#pragma unroll
            for (int j = 0; j < 4; ++j) acc[i][j] = MFMA16(a[i], b4[j], acc[i][j]);
        __builtin_amdgcn_s_setprio(0);

        if (h1) { VMF(0); }
        BAR();
    }

    // epilogue
    const int rlane = lane & 15;
    const int crow = m0 + wm * 128 + (lane >> 4) * 4;
    const int ccol = n0 + wn * 64 + rlane;
#pragma unroll
    for (int i = 0; i < 8; ++i) {
#pragma unroll
        for (int j = 0; j < 4; ++j) {
            const int nn = ccol + j * 16;
            if (nn >= Nlim) continue;
#pragma unroll
            for (int rr = 0; rr < 4; ++rr) {
                const int mm = crow + i * 16 + rr;
                C[(long)mm * ldc + nn] = acc[i][j][rr];
            }
        }
    }
}

// ---------------- host ----------------

extern "C" void kernel_launch(void* const* d_in, const int* in_sizes, int n_in,
                              void* d_out, int out_size, void* d_ws, size_t ws_size,
                              hipStream_t stream) {
    const float* h = (const float*)d_in[0];
    const float* W = (const float*)d_in[1];
    float* out = (float*)d_out;

    char* ws = (char*)d_ws;
    size_t off = 0;
    auto alloc = [&](size_t bytes) -> void* {
        void* p = ws + off;
        off += (bytes + 255) & ~(size_t)255;
        return p;
    };
    const size_t MD = (size_t)M1 * DD;
    u16* h_hi  = (u16*)alloc(MD * 2);
    u16* h_lo  = (u16*)alloc(MD * 2);
    u16* hW_hi = (u16*)alloc(MD * 2);
    u16* hW_lo = (u16*)alloc(MD * 2);
    u16* hT    = (u16*)alloc((size_t)BB * 1024 * SS * 2);
    u16* Wt_hi = (u16*)alloc((size_t)1024 * DD * 2);
    u16* Wt_lo = (u16*)alloc((size_t)1024 * DD * 2);
    float* scores = (float*)alloc((size_t)4 * SS * SS * 4);   // 4-batch fp32 chunk
    u16* attn8 = (u16*)alloc((size_t)M1 * SS * 2);            // 8-batch bf16 attn
    const bool use8 = (off <= ws_size);

    (void)hipFuncSetAttribute(reinterpret_cast<const void*>(&gemmS<1, 1>),
                              hipFuncAttributeMaxDynamicSharedMemorySize, 131072);
    (void)hipFuncSetAttribute(reinterpret_cast<const void*>(&gemmS<0, 0>),
                              hipFuncAttributeMaxDynamicSharedMemorySize, 131072);
    (void)hipFuncSetAttribute(reinterpret_cast<const void*>(&gemmT<128, 2, 0, 1>),
                              hipFuncAttributeMaxDynamicSharedMemorySize, 49152);
    (void)hipFuncSetAttribute(reinterpret_cast<const void*>(&gemmP),
                              hipFuncAttributeMaxDynamicSharedMemorySize, 65536);

    // prep: vectorized split, W split, transpose
    hsplit_kernel<<<dim3(M1 * 200 / 256), dim3(256), 0, stream>>>(h, h_hi, h_lo);
    wsplit_kernel<<<dim3(1024 * DD / 256), dim3(256), 0, stream>>>(W, Wt_hi, Wt_lo);
    transpose_kernel<<<dim3(SS / 32, 32, BB), dim3(32, 8), 0, stream>>>(h_hi, hT);

    // GEMM1: hW = h @ W  (M=16384 -> 64 tiles, N=1024pad -> 4 tiles, 25 K32)
    gemmS<1, 1><<<dim3(256), dim3(512), 131072, stream>>>(
        h_hi, h_lo, DD,
        Wt_hi, Wt_lo, 0L, DD,
        nullptr, hW_hi, hW_lo,
        DD, DD, 25, 64);

    for (int b0 = 0; b0 < BB; b0 += 4) {
        const long aoff = (long)b0 * SS * DD;
        // GEMM2: scores = hW @ h^T  (chunk M=8192 -> 32 tiles, N=2048 -> 8, 25 K32)
        gemmS<0, 0><<<dim3(256), dim3(512), 131072, stream>>>(
            hW_hi + aoff, hW_lo + aoff, DD,
            h_hi + aoff, h_lo + aoff, (long)SS * DD, DD,
            scores, nullptr, nullptr,
            SS, SS, 25, 32);
        if (use8) {
            // softmax -> compact bf16 attn8 (pitch 2048)
            softmax_kernel<<<dim3(4 * SS), dim3(256), 0, stream>>>(
                scores, attn8 + (long)b0 * SS * SS, 2048);
        } else {
            // fallback: in-place attn (pitch 4096 u16) + chunked PV
            softmax_kernel<<<dim3(4 * SS), dim3(256), 0, stream>>>(
                scores, (u16*)scores, 4096);
            gemmT<128, 2, 0, 1><<<dim3(448), dim3(256), 49152, stream>>>(
                (const u16*)scores, SS * 2,
                hT + (long)b0 * 1024 * SS, (long)1024 * SS, SS,
                out + (long)b0 * SS * DD,
                DD, DD, DD, 64, 64);
        }
    }

    if (use8) {
        // PV-8: out = attn8 @ h  (M=16384 -> 64 tiles, N=1024pad -> 4, K=2048)
        gemmP<<<dim3(256), dim3(512), 65536, stream>>>(
            attn8, SS,
            hT, (long)1024 * SS, SS,
            out, DD, DD, 64, 64);
    }
}

// Round 21
// 383.167 us; speedup vs baseline: 1.0297x; 1.0297x over previous
//
#include <hip/hip_runtime.h>
#include <hip/hip_bf16.h>
#include <stdint.h>

// ProjectiveAttention: out = softmax(h @ W @ h^T) @ h
// B=8, S=2048, D=800, all fp32 in/out.
// R10: conflict-free 32-wide swizzle. R12-R15: fused split3, single barrier,
// K=800 exact. R16/R19: gemmS BM=256 wave 128x64 streaming (80.8us, VERBATIM
// - R17/R18 proved touching its compilation context causes spill regression).
// R20: PV-8 null (attn8 doesn't fit proven ws budget; fallback ran) -> dropped.
// R21: R19 structure + properly-VECTORIZED fused split+transpose (hsplitT2):
// float4 loads, ushort4 hi/lo stores, LDS-transposed ushort4 hT stores.
// Deletes the 26MB h_hi re-read + one launch. (R15's fused attempt was
// scalar-store-bound; this one is full-rate on all three streams.)

#define BB 8
#define SS 2048
#define DD 800            // K = pitch = 800 u16 (1600B, 16B-aligned rows)
#define M1 (BB*SS)        // 16384

typedef unsigned short u16;
typedef __attribute__((ext_vector_type(8))) short bf16x8;
typedef __attribute__((ext_vector_type(4))) float f32x4;

#define MFMA16(A, B, C) __builtin_amdgcn_mfma_f32_16x16x32_bf16(A, B, C, 0, 0, 0)
#define VMF(N) asm volatile("s_waitcnt vmcnt(" #N ")" ::: "memory")
#define BAR() __builtin_amdgcn_s_barrier()

template <int SPW>
__device__ __forceinline__ void vmf_spw() {
    static_assert(SPW == 3 || SPW == 4 || SPW == 6, "unsupported SPW");
    if constexpr (SPW == 6) { VMF(6); }
    else if constexpr (SPW == 4) { VMF(4); }
    else { VMF(3); }
}

__device__ __forceinline__ u16 f2bf(float x) {
    uint32_t u = __float_as_uint(x);
    uint32_t r = (u + 0x7fffu + ((u >> 16) & 1u)) >> 16;  // RTN-even
    return (u16)r;
}
__device__ __forceinline__ float bf2f(u16 h) {
    return __uint_as_float(((uint32_t)h) << 16);
}
__device__ __forceinline__ void gload16(const void* g, void* l) {
    __builtin_amdgcn_global_load_lds((__attribute__((address_space(1))) void*)g,
                                     (__attribute__((address_space(3))) void*)l,
                                     16, 0, 0);
}

// ---------------- prep: fused split + transpose (vectorized) -------------------
// grid (64, 32, 8), block (8, 32). Per block: 32t x 32d tile.
// Phase 1: thread (q,ly) reads x[t0+ly][d0+4q..+3] as float4 (coalesced 128B),
//   stores hi/lo as ushort4 (coalesced 64B), stashes hv in LDS tile.
// Phase 2: thread (q,ly) writes hT[d0+ly][t0+4q..+3] as ushort4 (coalesced).
// d-quad guard: DD%4==0 so quads are fully in/out of range; pad rows zeroed.

__global__ __launch_bounds__(256) void hsplitT2_kernel(const float* __restrict__ x,
                                                       u16* __restrict__ hi,
                                                       u16* __restrict__ lo,
                                                       u16* __restrict__ hT) {
    __shared__ u16 tile[32][33];
    const int b = blockIdx.z;
    const int t0 = blockIdx.x * 32, d0 = blockIdx.y * 32;
    const int q = threadIdx.x;      // 0..7  (d quad)
    const int ly = threadIdx.y;     // 0..31 (t row / later d row)
    const int d = d0 + q * 4;

    ushort4 hv = {0, 0, 0, 0};
    if (d < DD) {
        const long off = ((long)b * SS + t0 + ly) * DD + d;
        float4 v = *(const float4*)(x + off);
        u16 h0 = f2bf(v.x), h1 = f2bf(v.y), h2 = f2bf(v.z), h3 = f2bf(v.w);
        hv = (ushort4){h0, h1, h2, h3};
        ushort4 lv = {f2bf(v.x - bf2f(h0)), f2bf(v.y - bf2f(h1)),
                      f2bf(v.z - bf2f(h2)), f2bf(v.w - bf2f(h3))};
        *(ushort4*)(hi + off) = hv;
        *(ushort4*)(lo + off) = lv;
    }
    tile[ly][q * 4 + 0] = hv.x;
    tile[ly][q * 4 + 1] = hv.y;
    tile[ly][q * 4 + 2] = hv.z;
    tile[ly][q * 4 + 3] = hv.w;
    __syncthreads();

    // phase 2: d-row = ly, t-quad = q
    ushort4 w = {tile[q * 4 + 0][ly], tile[q * 4 + 1][ly],
                 tile[q * 4 + 2][ly], tile[q * 4 + 3][ly]};
    *(ushort4*)(hT + ((long)b * 1024 + d0 + ly) * SS + t0 + q * 4) = w;
}

// W (fp32 [800][800]) -> Wt_hi/Wt_lo (bf16 [1024][800], transposed, pad rows 0)
__global__ __launch_bounds__(256) void wsplit_kernel(const float* __restrict__ W,
                                                     u16* __restrict__ hi,
                                                     u16* __restrict__ lo) {
    int idx = blockIdx.x * 256 + threadIdx.x;   // 1024*800
    int e = idx / DD, d = idx - e * DD;
    float v = (e < DD) ? W[(long)d * DD + e] : 0.f;
    u16 h = f2bf(v);
    hi[idx] = h;
    lo[idx] = f2bf(v - bf2f(h));
}

// ---------------- softmax (one block per row, in-place fp32 -> bf16 attn) ------

__global__ __launch_bounds__(256) void softmax_kernel(float* __restrict__ scores) {
    const long row = blockIdx.x;
    float* p = scores + row * (long)SS;
    const int tid = threadIdx.x;
    const int lane = tid & 63, wid = tid >> 6;
    __shared__ float red[8];

    float4 v0 = *(const float4*)(p + 8 * tid);
    float4 v1 = *(const float4*)(p + 8 * tid + 4);
    float v[8] = {v0.x, v0.y, v0.z, v0.w, v1.x, v1.y, v1.z, v1.w};
    float mx = -3.4e38f;
#pragma unroll
    for (int j = 0; j < 8; ++j) mx = fmaxf(mx, v[j]);
#pragma unroll
    for (int o = 32; o; o >>= 1) mx = fmaxf(mx, __shfl_xor(mx, o, 64));
    if (lane == 0) red[wid] = mx;
    __syncthreads();
    mx = fmaxf(fmaxf(red[0], red[1]), fmaxf(red[2], red[3]));

    float sum = 0.f;
#pragma unroll
    for (int j = 0; j < 8; ++j) { v[j] = __expf(v[j] - mx); sum += v[j]; }
#pragma unroll
    for (int o = 32; o; o >>= 1) sum += __shfl_xor(sum, o, 64);
    if (lane == 0) red[4 + wid] = sum;
    __syncthreads();
    const float inv = 1.f / (red[4] + red[5] + red[6] + red[7]);

    u16* attn = (u16*)p;
    ushort4 w0 = {f2bf(v[0] * inv), f2bf(v[1] * inv), f2bf(v[2] * inv), f2bf(v[3] * inv)};
    ushort4 w1 = {f2bf(v[4] * inv), f2bf(v[5] * inv), f2bf(v[6] * inv), f2bf(v[7] * inv)};
    *(ushort4*)(attn + 8 * tid) = w0;
    *(ushort4*)(attn + 8 * tid + 4) = w1;
}

// ---------------- gemmS: split3-fused, BM=256 x BN=256, BK=32, 8 waves ---------
// R19 VERBATIM (do not touch - R17/R18 spill lesson).

template <int SPLIT_OUT, int NGUARD>
__global__ __launch_bounds__(512, 2) void gemmS(
    const u16* __restrict__ Ahi, const u16* __restrict__ Alo, int lda,
    const u16* __restrict__ Bhi, const u16* __restrict__ Blo, long sB, int ldb,
    float* __restrict__ C, u16* __restrict__ Chi, u16* __restrict__ Clo,
    int ldc, int Nlim, int ksteps, int gmt) {
    extern __shared__ u16 smem[];          // [2][32768]

    const int tid = threadIdx.x;
    const int lane = tid & 63, wid = tid >> 6;
    const int wm = wid >> 2, wn = wid & 3;

    // bijective XCD remap (m204)
    const int nwg = gridDim.x;
    const int orig = blockIdx.x;
    const int q = nwg >> 3, r = nwg & 7;
    const int xcd = orig & 7;
    const int wg = (xcd < r ? xcd * (q + 1) : r * (q + 1) + (xcd - r) * q) + (orig >> 3);
    const int m0 = (wg % gmt) * 256;
    const int n0 = (wg / gmt) * 256;

    const long boff = sB ? (long)(m0 >> 11) * sB : 0;
    const u16* Bh = Bhi + boff;
    const u16* Bl = Blo + boff;

    const int sr = lane >> 2;
    const int sc = ((lane & 3) * 8) ^ (((lane >> 3) & 3) << 3);
    const int rdo = (lane & 15) * 32 + (((lane >> 4) * 8) ^ (((lane >> 1) & 3) << 3));

    // per-wave staging source (wave's 8 cells are all in one part)
    const int part = wid >> 1;             // 0 Ahi, 1 Alo, 2 Bhi, 3 Blo
    const u16* psrc = (part == 0) ? Ahi : (part == 1) ? Alo : (part == 2) ? Bh : Bl;
    const int pbase = (part < 2) ? m0 : n0;
    const int pld = (part < 2) ? lda : ldb;
    const int crow0 = (wid & 1) * 8;       // first local cell (of 16 in part)

    f32x4 acc[8][4];
#pragma unroll
    for (int i = 0; i < 8; ++i)
#pragma unroll
        for (int j = 0; j < 4; ++j) acc[i][j] = (f32x4){0.f, 0.f, 0.f, 0.f};

    auto stage = [&](int t, u16* bp) {
        const int kb = t * 32;
#pragma unroll
        for (int k = 0; k < 8; ++k) {
            const int c = crow0 + k;
            gload16(psrc + (long)(pbase + c * 16 + sr) * pld + kb + sc,
                    bp + (part * 16 + c) * 512 + lane * 8);
        }
    };

    stage(0, smem);
    VMF(0);
    BAR();

    for (int t = 0; t < ksteps; ++t) {
        u16* bp = smem + (t & 1) * 32768;
        const bool h1 = (t + 1 < ksteps);
        if (h1) stage(t + 1, smem + ((t + 1) & 1) * 32768);

        bf16x8 a[8], bh4[4], bl4[4];
#pragma unroll
        for (int j = 0; j < 4; ++j) {
            bh4[j] = *(const bf16x8*)(bp + (32 + wn * 4 + j) * 512 + rdo);
            bl4[j] = *(const bf16x8*)(bp + (48 + wn * 4 + j) * 512 + rdo);
        }
#pragma unroll
        for (int i = 0; i < 8; ++i)
            a[i] = *(const bf16x8*)(bp + (wm * 8 + i) * 512 + rdo);

        __builtin_amdgcn_s_setprio(1);
#pragma unroll
        for (int i = 0; i < 8; ++i)   // v0: hh
#pragma unroll
            for (int j = 0; j < 4; ++j) acc[i][j] = MFMA16(a[i], bh4[j], acc[i][j]);
#pragma unroll
        for (int i = 0; i < 8; ++i)   // v1: hl
#pragma unroll
            for (int j = 0; j < 4; ++j) acc[i][j] = MFMA16(a[i], bl4[j], acc[i][j]);
        __builtin_amdgcn_s_setprio(0);

#pragma unroll
        for (int i = 0; i < 8; ++i)   // reload: Alo (reuses a regs)
            a[i] = *(const bf16x8*)(bp + (16 + wm * 8 + i) * 512 + rdo);

        __builtin_amdgcn_s_setprio(1);
#pragma unroll
        for (int i = 0; i < 8; ++i)   // v2: lh
#pragma unroll
            for (int j = 0; j < 4; ++j) acc[i][j] = MFMA16(a[i], bh4[j], acc[i][j]);
        __builtin_amdgcn_s_setprio(0);

        if (h1) { VMF(0); }           // drains stage(t+1), issued ~full iter ago
        BAR();
    }

    // epilogue: C/D layout col=lane&15, row=(lane>>4)*4+reg (R1-verified)
    const int rlane = lane & 15;
    const int crow = m0 + wm * 128 + (lane >> 4) * 4;
    const int ccol = n0 + wn * 64 + rlane;
#pragma unroll
    for (int i = 0; i < 8; ++i) {
#pragma unroll
        for (int j = 0; j < 4; ++j) {
            const int nn = ccol + j * 16;
            if (NGUARD && nn >= Nlim) continue;
#pragma unroll
            for (int rr = 0; rr < 4; ++rr) {
                const int mm = crow + i * 16 + rr;
                const long off = (long)mm * ldc + nn;
                float v = acc[i][j][rr];
                if (SPLIT_OUT) {
                    u16 hh = f2bf(v);
                    Chi[off] = hh;
                    Clo[off] = f2bf(v - bf2f(hh));
                } else {
                    C[off] = v;
                }
            }
        }
    }
}

// ---------------- gemmT (PV): R19 verbatim -------------------------------------

template <int BN, int WN, int SPLIT_OUT, int NGUARD>
__global__ __launch_bounds__(128 * WN, 4) void gemmT(
    const u16* __restrict__ Ahi, int lda,
    const u16* __restrict__ Bhi, long sB, int ldb,
    float* __restrict__ C,
    int ldc, int Nlim, int Nbuf, int ksteps, int gmt) {
    constexpr int NCA = 8;
    constexpr int NCB = BN / 16;
    constexpr int BUFU = (NCA + NCB) * 512;
    constexpr int W = 2 * WN;
    constexpr int SPW = (NCA + NCB) / W;
    extern __shared__ u16 smem[];          // [3][BUFU]

    const int tid = threadIdx.x;
    const int lane = tid & 63, wid = tid >> 6;
    const int wm = wid / WN, wn = wid % WN;

    const int nwg = gridDim.x;
    const int orig = blockIdx.x;
    const int q = nwg >> 3, r = nwg & 7;
    const int xcd = orig & 7;
    const int wg = (xcd < r ? xcd * (q + 1) : r * (q + 1) + (xcd - r) * q) + (orig >> 3);
    const int m0 = (wg % gmt) * 128;
    const int n0 = (wg / gmt) * BN;

    const long boff = sB ? (long)(m0 >> 11) * sB : 0;
    const u16* Bh = Bhi + boff;

    const int sr = lane >> 2;
    const int sc = ((lane & 3) * 8) ^ (((lane >> 3) & 3) << 3);
    const int rdo = (lane & 15) * 32 + (((lane >> 4) * 8) ^ (((lane >> 1) & 3) << 3));

    f32x4 acc[4][4];
#pragma unroll
    for (int i = 0; i < 4; ++i)
#pragma unroll
        for (int j = 0; j < 4; ++j) acc[i][j] = (f32x4){0.f, 0.f, 0.f, 0.f};

    auto stage = [&](int t, u16* bp) {
        const int kb = t * 32;
        constexpr int APW = NCA / W, BPW = NCB / W;
#pragma unroll
        for (int i = 0; i < APW; ++i) {
            const int c = wid * APW + i;
            gload16(Ahi + (long)(m0 + c * 16 + sr) * lda + kb + sc,
                    bp + c * 512 + lane * 8);
        }
#pragma unroll
        for (int j = 0; j < BPW; ++j) {
            const int c = wid * BPW + j;
            gload16(Bh + (long)(n0 + c * 16 + sr) * ldb + kb + sc,
                    bp + (NCA + c) * 512 + lane * 8);
        }
    };

    stage(0, smem);
    if (ksteps > 1) stage(1, smem + BUFU);
    vmf_spw<SPW>();
    BAR();

    int bufi = 0;
    for (int t = 0; t < ksteps; ++t) {
        u16* bp = smem + bufi * BUFU;
        const bool h2 = (t + 2 < ksteps);
        if (h2) {
            int nb = bufi + 2; if (nb >= 3) nb -= 3;
            stage(t + 2, smem + nb * BUFU);
        }
        bf16x8 a[4], b[4];
#pragma unroll
        for (int i = 0; i < 4; ++i)
            a[i] = *(const bf16x8*)(bp + (wm * 4 + i) * 512 + rdo);
#pragma unroll
        for (int j = 0; j < 4; ++j)
            b[j] = *(const bf16x8*)(bp + (NCA + wn * 4 + j) * 512 + rdo);
        __builtin_amdgcn_s_setprio(1);
#pragma unroll
        for (int i = 0; i < 4; ++i)
#pragma unroll
            for (int j = 0; j < 4; ++j) acc[i][j] = MFMA16(a[i], b[j], acc[i][j]);
        __builtin_amdgcn_s_setprio(0);
        if (h2) {
            vmf_spw<SPW>();
        } else if (t + 1 < ksteps) {
            VMF(0);
        }
        BAR();
        ++bufi; if (bufi == 3) bufi = 0;
    }

    const int rlane = lane & 15;
    const int crow = m0 + wm * 64 + (lane >> 4) * 4;
    const int ccol = n0 + wn * 64 + rlane;
#pragma unroll
    for (int i = 0; i < 4; ++i) {
#pragma unroll
        for (int j = 0; j < 4; ++j) {
            const int nn = ccol + j * 16;
            if (NGUARD && nn >= Nbuf) continue;
#pragma unroll
            for (int rr = 0; rr < 4; ++rr) {
                const int mm = crow + i * 16 + rr;
                float v = acc[i][j][rr];
                if (NGUARD && nn >= Nlim) v = 0.f;
                C[(long)mm * ldc + nn] = v;
            }
        }
    }
}

// ---------------- host ----------------

extern "C" void kernel_launch(void* const* d_in, const int* in_sizes, int n_in,
                              void* d_out, int out_size, void* d_ws, size_t ws_size,
                              hipStream_t stream) {
    const float* h = (const float*)d_in[0];
    const float* W = (const float*)d_in[1];
    float* out = (float*)d_out;

    char* ws = (char*)d_ws;
    size_t off = 0;
    auto alloc = [&](size_t bytes) -> void* {
        void* p = ws + off;
        off += (bytes + 255) & ~(size_t)255;
        return p;
    };
    const size_t MD = (size_t)M1 * DD;
    u16* h_hi  = (u16*)alloc(MD * 2);
    u16* h_lo  = (u16*)alloc(MD * 2);
    u16* hW_hi = (u16*)alloc(MD * 2);
    u16* hW_lo = (u16*)alloc(MD * 2);
    u16* hT    = (u16*)alloc((size_t)BB * 1024 * SS * 2);
    u16* Wt_hi = (u16*)alloc((size_t)1024 * DD * 2);
    u16* Wt_lo = (u16*)alloc((size_t)1024 * DD * 2);
    float* scores = (float*)alloc((size_t)4 * SS * SS * 4);   // 4-batch chunk

    (void)hipFuncSetAttribute(reinterpret_cast<const void*>(&gemmS<1, 1>),
                              hipFuncAttributeMaxDynamicSharedMemorySize, 131072);
    (void)hipFuncSetAttribute(reinterpret_cast<const void*>(&gemmS<0, 0>),
                              hipFuncAttributeMaxDynamicSharedMemorySize, 131072);
    (void)hipFuncSetAttribute(reinterpret_cast<const void*>(&gemmT<128, 2, 0, 1>),
                              hipFuncAttributeMaxDynamicSharedMemorySize, 49152);

    // prep: fused vectorized split+transpose, W split
    hsplitT2_kernel<<<dim3(SS / 32, 32, BB), dim3(8, 32), 0, stream>>>(
        h, h_hi, h_lo, hT);
    wsplit_kernel<<<dim3(1024 * DD / 256), dim3(256), 0, stream>>>(W, Wt_hi, Wt_lo);

    // GEMM1: hW = h @ W  (M=16384 -> 64 tiles, N=1024pad -> 4 tiles, 25 K32)
    gemmS<1, 1><<<dim3(256), dim3(512), 131072, stream>>>(
        h_hi, h_lo, DD,
        Wt_hi, Wt_lo, 0L, DD,
        nullptr, hW_hi, hW_lo,
        DD, DD, 25, 64);

    for (int b0 = 0; b0 < BB; b0 += 4) {
        const long aoff = (long)b0 * SS * DD;
        // GEMM2: scores = hW @ h^T  (chunk M=8192 -> 32 tiles, N=2048 -> 8, 25 K32)
        gemmS<0, 0><<<dim3(256), dim3(512), 131072, stream>>>(
            hW_hi + aoff, hW_lo + aoff, DD,
            h_hi + aoff, h_lo + aoff, (long)SS * DD, DD,
            scores, nullptr, nullptr,
            SS, SS, 25, 32);
        // softmax rows -> bf16 attn in place (pitch 4096 u16)
        softmax_kernel<<<dim3(4 * SS), dim3(256), 0, stream>>>(scores);
        // PV: out = attn @ h  (chunk M=8192, N=7x128=896 -> guard at 800, K=2048)
        gemmT<128, 2, 0, 1><<<dim3(448), dim3(256), 49152, stream>>>(
            (const u16*)scores, SS * 2,
            hT + (long)b0 * 1024 * SS, (long)1024 * SS, SS,
            out + (long)b0 * SS * DD,
            DD, DD, DD, 64, 64);
    }
}